// Round 2
// baseline (260.175 us; speedup 1.0000x reference)
//
#include <hip/hip_runtime.h>
#include <hip/hip_bf16.h>

// h = x(65536x512) @ W^T(512x256) + bias_lin ; GroupNorm(8 groups of 32)
// ; min over 256 channels -> m[b] ; out[c*B+b] = m[b] + bias[c]
#define B_ROWS 65536
#define K_DIM  512
#define N_DIM  256
#define EPS    1e-5f
#define MTILE  32        // rows per block: 2048 blocks -> ~6 co-resident blocks/CU
#define LDS_STRIDE 264   // 256 k-half + 8 pad (bf16); 528B rows -> 2-way alias max (free)

using short8  = __attribute__((ext_vector_type(8))) short;
using floatx4 = __attribute__((ext_vector_type(4))) float;

__device__ __forceinline__ unsigned short f2bf(float f) {
    unsigned u = __builtin_bit_cast(unsigned, f);
    u += 0x7FFFu + ((u >> 16) & 1u);     // RNE
    return (unsigned short)(u >> 16);
}

// Pack W (256x512 fp32) into bf16 MFMA B-fragment order:
// P[((nt*16 + kk)*64 + lane)*8 + j] = bf16(W[nt*16 + (lane&15)][kk*32 + (lane>>4)*8 + j])
__global__ __launch_bounds__(64) void pack_w(const float* __restrict__ W,
                                             unsigned short* __restrict__ P) {
    int b    = blockIdx.x;           // 0..255
    int nt   = b >> 4, kk = b & 15;
    int lane = threadIdx.x;
    int l15  = lane & 15, quad = lane >> 4;
    const float* src = W + (size_t)(nt * 16 + l15) * K_DIM + kk * 32 + quad * 8;
    short8 v;
#pragma unroll
    for (int j = 0; j < 8; ++j) v[j] = (short)f2bf(src[j]);
    *(short8*)(P + ((size_t)(nt * 16 + kk) * 64 + lane) * 8) = v;
}

// One block = 32 rows x all 256 cols. Wave w owns cols [64w,64w+64) = groups 2w,2w+1.
// Fused: GEMM(bf16 MFMA) + bias + GroupNorm + min + broadcast write of out.
__global__ __launch_bounds__(256, 6) void gemm_gn_min_bcast(
    const float* __restrict__ X, const unsigned short* __restrict__ P,
    const float* __restrict__ bias_lin, const float* __restrict__ wgn,
    const float* __restrict__ bgn, const float* __restrict__ bias,
    float* __restrict__ out)
{
    __shared__ unsigned short Ash[MTILE * LDS_STRIDE];   // 16896 B
    __shared__ float sm_min[4][MTILE];                   // 512 B
    __shared__ float m_sh[MTILE];                        // 128 B

    const int tid  = threadIdx.x;
    const int wave = tid >> 6, lane = tid & 63;
    const int l15  = lane & 15, quad = lane >> 4;
    const size_t row0 = (size_t)blockIdx.x * MTILE;

    floatx4 acc[2][4] = {};   // [row-tile][col-tile]; D: col=lane&15, row=quad*4+reg

    for (int kh = 0; kh < 2; ++kh) {           // two K=256 halves staged in LDS
        if (kh) __syncthreads();               // all waves done reading previous half
        // stage 32 rows x 256 k : fp32 global (coalesced float4) -> bf16 LDS
        for (int i = tid; i < MTILE * 64; i += 256) {
            int r = i >> 6, c4 = (i & 63) << 2;
            const float4 f = *(const float4*)(X + (row0 + r) * K_DIM + kh * 256 + c4);
            ushort4 h;
            h.x = f2bf(f.x); h.y = f2bf(f.y); h.z = f2bf(f.z); h.w = f2bf(f.w);
            *(ushort4*)(&Ash[r * LDS_STRIDE + c4]) = h;
        }
        __syncthreads();

#pragma unroll
        for (int kk = 0; kk < 8; ++kk) {
            const int kkg = kh * 8 + kk;
            short8 a[2], b[4];
#pragma unroll
            for (int rt = 0; rt < 2; ++rt)
                a[rt] = *(const short8*)&Ash[(rt * 16 + l15) * LDS_STRIDE + kk * 32 + quad * 8];
#pragma unroll
            for (int ct = 0; ct < 4; ++ct) {
                int nt = wave * 4 + ct;
                b[ct] = *(const short8*)(P + (((size_t)nt * 16 + kkg) * 64 + lane) * 8);
            }
#pragma unroll
            for (int rt = 0; rt < 2; ++rt)
#pragma unroll
                for (int ct = 0; ct < 4; ++ct)
                    acc[rt][ct] = __builtin_amdgcn_mfma_f32_16x16x32_bf16(
                        a[rt], b[ct], acc[rt][ct], 0, 0, 0);
        }
    }

    // per-column params (16 distinct per wave -> broadcasty L2 loads)
    float bl[4], wg[4], bg[4];
#pragma unroll
    for (int ct = 0; ct < 4; ++ct) {
        int col = wave * 64 + ct * 16 + l15;
        bl[ct] = bias_lin[col]; wg[ct] = wgn[col]; bg[ct] = bgn[col];
    }

#pragma unroll
    for (int rt = 0; rt < 2; ++rt) {
#pragma unroll
        for (int reg = 0; reg < 4; ++reg) {
            float v[4];
#pragma unroll
            for (int ct = 0; ct < 4; ++ct) v[ct] = acc[rt][ct][reg] + bl[ct];
            float rmin = 1e30f;
#pragma unroll
            for (int h = 0; h < 2; ++h) {   // two 32-ch groups per wave
                float va = v[2 * h], vb = v[2 * h + 1];
                float s = va + vb, ss = va * va + vb * vb;
#pragma unroll
                for (int m = 1; m < 16; m <<= 1) {   // 16-lane butterfly (in-group)
                    s  += __shfl_xor(s, m);
                    ss += __shfl_xor(ss, m);
                }
                float mean = s * (1.0f / 32.0f);
                float var  = ss * (1.0f / 32.0f) - mean * mean;
                float inv  = rsqrtf(var + EPS);
                float ga = (va - mean) * inv * wg[2 * h]     + bg[2 * h];
                float gb = (vb - mean) * inv * wg[2 * h + 1] + bg[2 * h + 1];
                float mn = fminf(ga, gb);
#pragma unroll
                for (int m = 1; m < 16; m <<= 1) mn = fminf(mn, __shfl_xor(mn, m));
                rmin = fminf(rmin, mn);
            }
            if (l15 == 0) sm_min[wave][rt * 16 + quad * 4 + reg] = rmin;
        }
    }
    __syncthreads();
    if (tid < MTILE)
        m_sh[tid] = fminf(fminf(sm_min[0][tid], sm_min[1][tid]),
                          fminf(sm_min[2][tid], sm_min[3][tid]));
    __syncthreads();

    // broadcast write: out[c*B + row0 + j] = m[j] + bias[c], 32 rows x 256 c.
    // tid -> (cgrp = tid>>3 gives 32 c's/pass, lane8 = tid&7 gives 128B-contig float4s)
    const int lane8 = tid & 7, cgrp = tid >> 3;
    float4 mv = *(const float4*)&m_sh[lane8 * 4];
#pragma unroll
    for (int pass = 0; pass < 8; ++pass) {
        int c = pass * 32 + cgrp;
        float bc = bias[c];
        float4 o;
        o.x = mv.x + bc; o.y = mv.y + bc; o.z = mv.z + bc; o.w = mv.w + bc;
        *(float4*)(out + (size_t)c * B_ROWS + row0 + lane8 * 4) = o;
    }
}

extern "C" void kernel_launch(void* const* d_in, const int* in_sizes, int n_in,
                              void* d_out, int out_size, void* d_ws, size_t ws_size,
                              hipStream_t stream) {
    const float* x    = (const float*)d_in[0];
    const float* w    = (const float*)d_in[1];
    const float* bl   = (const float*)d_in[2];
    const float* wg   = (const float*)d_in[3];
    const float* bg   = (const float*)d_in[4];
    const float* bias = (const float*)d_in[5];

    unsigned short* P = (unsigned short*)d_ws;     // 256 KB packed bf16 W
    float* out = (float*)d_out;

    hipLaunchKernelGGL(pack_w, dim3(256), dim3(64), 0, stream, w, P);
    hipLaunchKernelGGL(gemm_gn_min_bcast, dim3(B_ROWS / MTILE), dim3(256), 0, stream,
                       x, P, bl, wg, bg, bias, out);
}

// Round 3
// 236.277 us; speedup vs baseline: 1.1011x; 1.1011x over previous
//
#include <hip/hip_runtime.h>
#include <hip/hip_bf16.h>

// h = x(65536x512) @ W^T(512x256) + bias_lin ; GroupNorm(8 groups of 32)
// ; min over 256 channels -> m[b] ; out[c*B+b] = m[b] + bias[c]
//
// Persistent design: grid=256 blocks x 512 threads (8 waves). Wave w owns
// channel group w (cols 32w..32w+31) and holds ALL its W fragments in
// registers (32 short8 = 128 VGPRs), loaded once. K-loop = ds_read + MFMA
// only. Each block loops over 8 row-tiles of 32, prefetching the next x
// tile into registers while computing the current one.
#define B_ROWS 65536
#define K_DIM  512
#define N_DIM  256
#define EPS    1e-5f
#define MTILE  32
#define NBLK   256
#define STRIDE 520      // 512 + 8 pad (bf16 elems); 1040B rows -> 2-way alias max (free)

using short8  = __attribute__((ext_vector_type(8))) short;
using floatx4 = __attribute__((ext_vector_type(4))) float;

__device__ __forceinline__ unsigned short f2bf(float f) {
    unsigned u = __builtin_bit_cast(unsigned, f);
    u += 0x7FFFu + ((u >> 16) & 1u);     // RNE
    return (unsigned short)(u >> 16);
}

// Pack W (256x512 fp32) into bf16 MFMA B-fragment order:
// P[((nt*16 + kkg)*64 + lane)*8 + j] = bf16(W[nt*16 + (lane&15)][kkg*32 + (lane>>4)*8 + j])
__global__ __launch_bounds__(64) void pack_w(const float* __restrict__ W,
                                             unsigned short* __restrict__ P) {
    int b    = blockIdx.x;           // 0..255
    int nt   = b >> 4, kk = b & 15;
    int lane = threadIdx.x;
    int l15  = lane & 15, quad = lane >> 4;
    const float* src = W + (size_t)(nt * 16 + l15) * K_DIM + kk * 32 + quad * 8;
    short8 v;
#pragma unroll
    for (int j = 0; j < 8; ++j) v[j] = (short)f2bf(src[j]);
    *(short8*)(P + ((size_t)(nt * 16 + kk) * 64 + lane) * 8) = v;
}

__global__ __launch_bounds__(512, 2) void fused_persistent(
    const float* __restrict__ X, const unsigned short* __restrict__ P,
    const float* __restrict__ bias_lin, const float* __restrict__ wgn,
    const float* __restrict__ bgn, const float* __restrict__ bias,
    float* __restrict__ out)
{
    __shared__ unsigned short Ash[MTILE * STRIDE];   // 33280 B
    __shared__ float sm_min[8][MTILE];               // 1024 B
    __shared__ float m_sh[MTILE];                    // 128 B

    const int tid  = threadIdx.x;
    const int wave = tid >> 6, lane = tid & 63;
    const int l15  = lane & 15, quad = lane >> 4;

    // ---- load ALL of this wave's W fragments into registers (once) ----
    short8 bfr[2][16];
#pragma unroll
    for (int ct = 0; ct < 2; ++ct)
#pragma unroll
        for (int kkg = 0; kkg < 16; ++kkg) {
            int nt = 2 * wave + ct;
            bfr[ct][kkg] = *(const short8*)(P + (((size_t)nt * 16 + kkg) * 64 + lane) * 8);
        }

    // per-column params (hoisted; col = wave*32 + ct*16 + l15)
    float bl[2], wg[2], bg[2];
#pragma unroll
    for (int ct = 0; ct < 2; ++ct) {
        int col = wave * 32 + ct * 16 + l15;
        bl[ct] = bias_lin[col]; wg[ct] = wgn[col]; bg[ct] = bgn[col];
    }
    // bcast-channel biases (c = pass*64 + (tid>>3))
    float bias_r[4];
#pragma unroll
    for (int pass = 0; pass < 4; ++pass) bias_r[pass] = bias[pass * 64 + (tid >> 3)];

    // staging geometry: tile = 32 rows x 128 float4; thread covers
    // rows r0+4p (r0 = tid>>7), cols [c4, c4+4) fp32 (c4 = (tid&127)*4)
    const int r0 = tid >> 7;
    const int c4 = (tid & 127) * 4;

    const int tiles = B_ROWS / MTILE;    // 2048
    int t = blockIdx.x;

    // prefetch tile 0
    float4 xq[8];
#pragma unroll
    for (int p = 0; p < 8; ++p)
        xq[p] = *(const float4*)(X + (size_t)(t * MTILE + r0 + 4 * p) * K_DIM + c4);

    for (; t < tiles; t += NBLK) {
        // ---- convert + stage into LDS ----
#pragma unroll
        for (int p = 0; p < 8; ++p) {
            ushort4 h;
            h.x = f2bf(xq[p].x); h.y = f2bf(xq[p].y);
            h.z = f2bf(xq[p].z); h.w = f2bf(xq[p].w);
            *(ushort4*)(&Ash[(r0 + 4 * p) * STRIDE + c4]) = h;
        }
        __syncthreads();

        // ---- prefetch next tile (overlaps compute + epilogue) ----
        int tn = t + NBLK;
        if (tn < tiles) {
#pragma unroll
            for (int p = 0; p < 8; ++p)
                xq[p] = *(const float4*)(X + (size_t)(tn * MTILE + r0 + 4 * p) * K_DIM + c4);
        }

        // ---- K-loop: pure LDS + MFMA ----
        floatx4 acc[2][2] = {};
#pragma unroll
        for (int kk = 0; kk < 16; ++kk) {
            short8 a0 = *(const short8*)&Ash[(l15)      * STRIDE + kk * 32 + quad * 8];
            short8 a1 = *(const short8*)&Ash[(16 + l15) * STRIDE + kk * 32 + quad * 8];
            acc[0][0] = __builtin_amdgcn_mfma_f32_16x16x32_bf16(a0, bfr[0][kk], acc[0][0], 0, 0, 0);
            acc[0][1] = __builtin_amdgcn_mfma_f32_16x16x32_bf16(a0, bfr[1][kk], acc[0][1], 0, 0, 0);
            acc[1][0] = __builtin_amdgcn_mfma_f32_16x16x32_bf16(a1, bfr[0][kk], acc[1][0], 0, 0, 0);
            acc[1][1] = __builtin_amdgcn_mfma_f32_16x16x32_bf16(a1, bfr[1][kk], acc[1][1], 0, 0, 0);
        }

        // ---- epilogue: bias + groupnorm (group = this wave's 32 cols) + min ----
#pragma unroll
        for (int rt = 0; rt < 2; ++rt) {
#pragma unroll
            for (int reg = 0; reg < 4; ++reg) {
                float va = acc[rt][0][reg] + bl[0];
                float vb = acc[rt][1][reg] + bl[1];
                float s = va + vb, ss = va * va + vb * vb;
#pragma unroll
                for (int m = 1; m < 16; m <<= 1) {   // 16-lane butterfly (in-quad)
                    s  += __shfl_xor(s, m);
                    ss += __shfl_xor(ss, m);
                }
                float mean = s * (1.0f / 32.0f);
                float var  = ss * (1.0f / 32.0f) - mean * mean;
                float inv  = rsqrtf(var + EPS);
                float ga = (va - mean) * inv * wg[0] + bg[0];
                float gb = (vb - mean) * inv * wg[1] + bg[1];
                float mn = fminf(ga, gb);
#pragma unroll
                for (int m = 1; m < 16; m <<= 1) mn = fminf(mn, __shfl_xor(mn, m));
                if (l15 == 0) sm_min[wave][rt * 16 + quad * 4 + reg] = mn;
            }
        }
        __syncthreads();
        if (tid < MTILE) {
            float m0 = sm_min[0][tid];
#pragma unroll
            for (int w = 1; w < 8; ++w) m0 = fminf(m0, sm_min[w][tid]);
            m_sh[tid] = m0;
        }
        __syncthreads();

        // ---- broadcast write: out[c*B + t*32 + j] = m[j] + bias[c] ----
        float4 mv = *(const float4*)&m_sh[(tid & 7) * 4];
#pragma unroll
        for (int pass = 0; pass < 4; ++pass) {
            int c = pass * 64 + (tid >> 3);
            float bc = bias_r[pass];
            float4 o;
            o.x = mv.x + bc; o.y = mv.y + bc; o.z = mv.z + bc; o.w = mv.w + bc;
            *(float4*)(out + (size_t)c * B_ROWS + t * MTILE + (tid & 7) * 4) = o;
        }
        // next iteration's Ash write is safe: every wave passed the two
        // epilogue barriers, which postdate all Ash reads.
    }
}

extern "C" void kernel_launch(void* const* d_in, const int* in_sizes, int n_in,
                              void* d_out, int out_size, void* d_ws, size_t ws_size,
                              hipStream_t stream) {
    const float* x    = (const float*)d_in[0];
    const float* w    = (const float*)d_in[1];
    const float* bl   = (const float*)d_in[2];
    const float* wg   = (const float*)d_in[3];
    const float* bg   = (const float*)d_in[4];
    const float* bias = (const float*)d_in[5];

    unsigned short* P = (unsigned short*)d_ws;     // 256 KB packed bf16 W
    float* out = (float*)d_out;

    hipLaunchKernelGGL(pack_w, dim3(256), dim3(64), 0, stream, w, P);
    hipLaunchKernelGGL(fused_persistent, dim3(NBLK), dim3(512), 0, stream,
                       x, P, bl, wg, bg, bias, out);
}